// Round 5
// baseline (85.624 us; speedup 1.0000x reference)
//
#include <hip/hip_runtime.h>
#include <hip/hip_bf16.h>

#define D 512            // d_in == d_out == 512
#define NROWS 65536      // output rows
#define CAP 32           // per-row bucket capacity (Poisson mean 8; P(>32) ~ 1e-10)
#define OVFCAP 4096      // overflow spill capacity

typedef float f32x4 __attribute__((ext_vector_type(4)));
typedef int   i32x4 __attribute__((ext_vector_type(4)));

// ---------- fused setup: zero counts+ovf (blocks 0..63, int4) + transpose w -> bf16 wT (64..319) ----------
__global__ __launch_bounds__(256) void k_setup(const float* __restrict__ w,
                                               __hip_bfloat16* __restrict__ wt,
                                               int* __restrict__ counts,
                                               int* __restrict__ ovf_cnt) {
    __shared__ float tile[32][33];
    int b = blockIdx.x;
    int t = threadIdx.x;
    if (b < 64) {
        i32x4 z = {0, 0, 0, 0};
        ((i32x4*)counts)[b * 256 + t] = z;
        if (b == 0 && t == 0) *ovf_cnt = 0;
        return;
    }
    b -= 64;                        // 256 transpose tiles: 16x16 grid of 32x32 tiles
    int bx = b & 15, by = b >> 4;
    int tx = t & 31, ty = t >> 5;   // 32 x 8
    for (int i = ty; i < 32; i += 8)
        tile[i][tx] = __builtin_nontemporal_load(&w[(by * 32 + i) * D + bx * 32 + tx]);
    __syncthreads();
    for (int i = ty; i < 32; i += 8)
        wt[(bx * 32 + i) * D + by * 32 + tx] = __float2bfloat16(tile[tx][i]);
}

// ---------- direct bucket scatter: 4 nnz per thread ----------
__global__ __launch_bounds__(256) void k_bucket(const int* __restrict__ rows,
                                                const int* __restrict__ cols,
                                                const float* __restrict__ vals, int nnz,
                                                int* __restrict__ counts, uint2* __restrict__ bucket,
                                                int* __restrict__ ovf_cnt, uint4* __restrict__ ovf) {
    int i = blockIdx.x * blockDim.x + threadIdx.x;
    int base = i * 4;
    int r[4], c[4];
    float v[4];
    int m;
    if (base + 3 < nnz) {
        i32x4 rr = __builtin_nontemporal_load(&((const i32x4*)rows)[i]);
        i32x4 cc = __builtin_nontemporal_load(&((const i32x4*)cols)[i]);
        f32x4 vv = __builtin_nontemporal_load(&((const f32x4*)vals)[i]);
        r[0] = rr.x; r[1] = rr.y; r[2] = rr.z; r[3] = rr.w;
        c[0] = cc.x; c[1] = cc.y; c[2] = cc.z; c[3] = cc.w;
        v[0] = vv.x; v[1] = vv.y; v[2] = vv.z; v[3] = vv.w;
        m = 4;
    } else {
        m = nnz - base;
        if (m <= 0) return;
        for (int k = 0; k < m; ++k) {
            r[k] = rows[base + k];
            c[k] = cols[base + k];
            v[k] = vals[base + k];
        }
    }
    for (int k = 0; k < m; ++k) {
        int pos = atomicAdd(&counts[r[k]], 1);
        if (pos < CAP) {
            bucket[(size_t)r[k] * CAP + pos] = make_uint2((unsigned)c[k], __float_as_uint(v[k]));
        } else {
            int o = atomicAdd(ovf_cnt, 1);
            if (o < OVFCAP)
                ovf[o] = make_uint4((unsigned)r[k], (unsigned)c[k], __float_as_uint(v[k]), 0u);
        }
    }
}

// ---------- main compute: one wave (64 lanes) per output row, bf16 weight gather; inline overflow fix ----------
__global__ __launch_bounds__(256) void k_spmm(const int* __restrict__ counts,
                                              const uint2* __restrict__ bucket,
                                              const uint4* __restrict__ wt4,   // bf16 wT, 64 uint4/row
                                              const f32x4* __restrict__ bias4,
                                              f32x4* __restrict__ out,
                                              const int* __restrict__ ovf_cnt,
                                              const uint4* __restrict__ ovf) {
    int wid = (int)((blockIdx.x * blockDim.x + threadIdx.x) >> 6);  // = row
    int lane = threadIdx.x & 63;
    f32x4 a0 = bias4[lane * 2];
    f32x4 a1 = bias4[lane * 2 + 1];
    int cnt = counts[wid];
    int novf = *ovf_cnt;                 // uniformly 0 in practice (broadcast load)
    if (cnt > CAP) cnt = CAP;
    // preload this row's pairs: lane i holds pair i (one coalesced load)
    uint2 mypair = make_uint2(0u, 0u);
    if (lane < cnt) mypair = bucket[(size_t)wid * CAP + lane];
    for (int s = 0; s < cnt; ++s) {
        unsigned c = (unsigned)__shfl((int)mypair.x, s);
        float v = __uint_as_float(__shfl((int)mypair.y, s));
        uint4 wb = wt4[(size_t)c * 64 + lane];
        f32x4 w0, w1;
        w0.x = __uint_as_float(wb.x << 16);
        w0.y = __uint_as_float(wb.x & 0xffff0000u);
        w0.z = __uint_as_float(wb.y << 16);
        w0.w = __uint_as_float(wb.y & 0xffff0000u);
        w1.x = __uint_as_float(wb.z << 16);
        w1.y = __uint_as_float(wb.z & 0xffff0000u);
        w1.z = __uint_as_float(wb.w << 16);
        w1.w = __uint_as_float(wb.w & 0xffff0000u);
        a0 += v * w0;
        a1 += v * w1;
    }
    if (novf > 0) {                      // rare path: scan spill list for this row
        if (novf > OVFCAP) novf = OVFCAP;
        for (int e = 0; e < novf; ++e) {
            uint4 p = ovf[e];
            if ((int)p.x == wid) {
                float v = __uint_as_float(p.z);
                uint4 wb = wt4[(size_t)p.y * 64 + lane];
                f32x4 w0, w1;
                w0.x = __uint_as_float(wb.x << 16);
                w0.y = __uint_as_float(wb.x & 0xffff0000u);
                w0.z = __uint_as_float(wb.y << 16);
                w0.w = __uint_as_float(wb.y & 0xffff0000u);
                w1.x = __uint_as_float(wb.z << 16);
                w1.y = __uint_as_float(wb.z & 0xffff0000u);
                w1.z = __uint_as_float(wb.w << 16);
                w1.w = __uint_as_float(wb.w & 0xffff0000u);
                a0 += v * w0;
                a1 += v * w1;
            }
        }
    }
    f32x4* op = out + (size_t)wid * (D / 4);
    __builtin_nontemporal_store(a0, &op[lane * 2]);
    __builtin_nontemporal_store(a1, &op[lane * 2 + 1]);
}

// ---------- fallback path (tiny workspace): init out with bias, atomic scatter ----------
__global__ void k_init_bias(const float* __restrict__ bias, float* __restrict__ out, int total) {
    int i = blockIdx.x * blockDim.x + threadIdx.x;
    if (i < total) out[i] = bias[i & (D - 1)];
}

__global__ void k_atomic_spmm(const int* __restrict__ rows, const int* __restrict__ cols,
                              const float* __restrict__ vals, int nnz,
                              const float* __restrict__ w, float* __restrict__ out) {
    int wid = (int)((blockIdx.x * blockDim.x + threadIdx.x) >> 6);
    if (wid >= nnz) return;
    int lane = threadIdx.x & 63;
    int r = rows[wid];
    int c = cols[wid];
    float v = vals[wid];
    float* op = out + (size_t)r * D + lane * 8;
#pragma unroll
    for (int k = 0; k < 8; ++k) {
        float wv = w[(size_t)(lane * 8 + k) * D + c];
        atomicAdd(&op[k], v * wv);
    }
}

extern "C" void kernel_launch(void* const* d_in, const int* in_sizes, int n_in,
                              void* d_out, int out_size, void* d_ws, size_t ws_size,
                              hipStream_t stream) {
    const int*   rows   = (const int*)d_in[0];
    const int*   cols   = (const int*)d_in[1];
    const float* vals   = (const float*)d_in[2];
    const float* weight = (const float*)d_in[3];
    const float* bias   = (const float*)d_in[4];
    float*       out    = (float*)d_out;
    const int nnz = in_sizes[0];

    // workspace carve-out
    char* ws = (char*)d_ws;
    size_t off = 0;
    auto alloc = [&](size_t bytes) -> void* {
        off = (off + 255) & ~(size_t)255;
        void* p = ws + off;
        off += bytes;
        return p;
    };
    __hip_bfloat16* wT = (__hip_bfloat16*)alloc((size_t)D * D * sizeof(__hip_bfloat16)); // 512 KiB
    int*   counts  = (int*)  alloc((size_t)NROWS * sizeof(int));                // 256 KiB
    int*   ovf_cnt = (int*)  alloc(256);                                        // 1 int
    uint4* ovf     = (uint4*)alloc((size_t)OVFCAP * sizeof(uint4));             // 64 KiB
    uint2* bucket  = (uint2*)alloc((size_t)NROWS * CAP * sizeof(uint2));        // 16 MiB
    const size_t need_full = off;

    if (need_full <= ws_size) {
        // ---- bucket path: 3 dispatches ----
        k_setup<<<320, 256, 0, stream>>>(weight, wT, counts, ovf_cnt);
        k_bucket<<<((nnz + 3) / 4 + 255) / 256, 256, 0, stream>>>(rows, cols, vals, nnz,
                                                                  counts, bucket, ovf_cnt, ovf);
        k_spmm<<<NROWS / 4, 256, 0, stream>>>(counts, bucket, (const uint4*)wT,
                                              (const f32x4*)bias, (f32x4*)out, ovf_cnt, ovf);
    } else {
        // ---- atomic fallback, direct (strided) weight reads ----
        k_init_bias<<<(out_size + 255) / 256, 256, 0, stream>>>(bias, out, out_size);
        k_atomic_spmm<<<((size_t)nnz * 64 + 255) / 256, 256, 0, stream>>>(rows, cols, vals, nnz, weight, out);
    }
}

// Round 6
// 81.396 us; speedup vs baseline: 1.0519x; 1.0519x over previous
//
#include <hip/hip_runtime.h>
#include <hip/hip_bf16.h>

#define D 512            // d_in == d_out == 512
#define NROWS 65536      // output rows
#define CAP 32           // per-row bucket capacity (Poisson mean 8; P(>32) ~ 1e-10)
#define OVFCAP 4096      // overflow spill capacity

typedef float f32x4 __attribute__((ext_vector_type(4)));
typedef int   i32x4 __attribute__((ext_vector_type(4)));

// ---------- zero counts + ovf_cnt (fast, precedes bucket) ----------
__global__ __launch_bounds__(256) void k_zero(int* __restrict__ counts,
                                              int* __restrict__ ovf_cnt) {
    int i = blockIdx.x * 256 + threadIdx.x;
    i32x4 z = {0, 0, 0, 0};
    ((i32x4*)counts)[i] = z;
    if (i == 0) *ovf_cnt = 0;
}

// ---------- fused: transpose w -> bf16 wT (blocks 0..255) + bucket scatter (blocks 256..) ----------
__global__ __launch_bounds__(256) void k_bucket(const float* __restrict__ w,
                                                __hip_bfloat16* __restrict__ wt,
                                                const int* __restrict__ rows,
                                                const int* __restrict__ cols,
                                                const float* __restrict__ vals, int nnz,
                                                int* __restrict__ counts, uint2* __restrict__ bucket,
                                                int* __restrict__ ovf_cnt, uint4* __restrict__ ovf) {
    int b = blockIdx.x;
    int t = threadIdx.x;
    if (b < 256) {
        // transpose tile: 16x16 grid of 32x32 tiles
        __shared__ float tile[32][33];
        int bx = b & 15, by = b >> 4;
        int tx = t & 31, ty = t >> 5;   // 32 x 8
        for (int i = ty; i < 32; i += 8)
            tile[i][tx] = __builtin_nontemporal_load(&w[(by * 32 + i) * D + bx * 32 + tx]);
        __syncthreads();
        for (int i = ty; i < 32; i += 8)
            wt[(bx * 32 + i) * D + by * 32 + tx] = __float2bfloat16(tile[tx][i]);
        return;
    }
    int i = (b - 256) * 256 + t;        // 1 nnz per thread: max wave parallelism for the
    if (i >= nnz) return;               // latency-bound atomic + dependent scatter store
    int r = __builtin_nontemporal_load(&rows[i]);
    int c = __builtin_nontemporal_load(&cols[i]);
    float v = __builtin_nontemporal_load(&vals[i]);
    int pos = atomicAdd(&counts[r], 1);
    if (pos < CAP) {
        bucket[(size_t)r * CAP + pos] = make_uint2((unsigned)c, __float_as_uint(v));
    } else {
        int o = atomicAdd(ovf_cnt, 1);
        if (o < OVFCAP)
            ovf[o] = make_uint4((unsigned)r, (unsigned)c, __float_as_uint(v), 0u);
    }
}

// ---------- main compute: one wave (64 lanes) per output row, bf16 weight gather; inline overflow fix ----------
__global__ __launch_bounds__(256) void k_spmm(const int* __restrict__ counts,
                                              const uint2* __restrict__ bucket,
                                              const uint4* __restrict__ wt4,   // bf16 wT, 64 uint4/row
                                              const f32x4* __restrict__ bias4,
                                              f32x4* __restrict__ out,
                                              const int* __restrict__ ovf_cnt,
                                              const uint4* __restrict__ ovf) {
    int wid = (int)((blockIdx.x * blockDim.x + threadIdx.x) >> 6);  // = row
    int lane = threadIdx.x & 63;
    f32x4 a0 = bias4[lane * 2];
    f32x4 a1 = bias4[lane * 2 + 1];
    int cnt = counts[wid];
    int novf = *ovf_cnt;                 // uniformly 0 in practice (broadcast load)
    if (cnt > CAP) cnt = CAP;
    // preload this row's pairs: lane i holds pair i (one coalesced load)
    uint2 mypair = make_uint2(0u, 0u);
    if (lane < cnt) mypair = bucket[(size_t)wid * CAP + lane];
    for (int s = 0; s < cnt; ++s) {
        unsigned c = (unsigned)__shfl((int)mypair.x, s);
        float v = __uint_as_float(__shfl((int)mypair.y, s));
        uint4 wb = wt4[(size_t)c * 64 + lane];
        f32x4 w0, w1;
        w0.x = __uint_as_float(wb.x << 16);
        w0.y = __uint_as_float(wb.x & 0xffff0000u);
        w0.z = __uint_as_float(wb.y << 16);
        w0.w = __uint_as_float(wb.y & 0xffff0000u);
        w1.x = __uint_as_float(wb.z << 16);
        w1.y = __uint_as_float(wb.z & 0xffff0000u);
        w1.z = __uint_as_float(wb.w << 16);
        w1.w = __uint_as_float(wb.w & 0xffff0000u);
        a0 += v * w0;
        a1 += v * w1;
    }
    if (novf > 0) {                      // rare path: scan spill list for this row
        if (novf > OVFCAP) novf = OVFCAP;
        for (int e = 0; e < novf; ++e) {
            uint4 p = ovf[e];
            if ((int)p.x == wid) {
                float v = __uint_as_float(p.z);
                uint4 wb = wt4[(size_t)p.y * 64 + lane];
                f32x4 w0, w1;
                w0.x = __uint_as_float(wb.x << 16);
                w0.y = __uint_as_float(wb.x & 0xffff0000u);
                w0.z = __uint_as_float(wb.y << 16);
                w0.w = __uint_as_float(wb.y & 0xffff0000u);
                w1.x = __uint_as_float(wb.z << 16);
                w1.y = __uint_as_float(wb.z & 0xffff0000u);
                w1.z = __uint_as_float(wb.w << 16);
                w1.w = __uint_as_float(wb.w & 0xffff0000u);
                a0 += v * w0;
                a1 += v * w1;
            }
        }
    }
    f32x4* op = out + (size_t)wid * (D / 4);
    __builtin_nontemporal_store(a0, &op[lane * 2]);
    __builtin_nontemporal_store(a1, &op[lane * 2 + 1]);
}

// ---------- fallback path (tiny workspace): init out with bias, atomic scatter ----------
__global__ void k_init_bias(const float* __restrict__ bias, float* __restrict__ out, int total) {
    int i = blockIdx.x * blockDim.x + threadIdx.x;
    if (i < total) out[i] = bias[i & (D - 1)];
}

__global__ void k_atomic_spmm(const int* __restrict__ rows, const int* __restrict__ cols,
                              const float* __restrict__ vals, int nnz,
                              const float* __restrict__ w, float* __restrict__ out) {
    int wid = (int)((blockIdx.x * blockDim.x + threadIdx.x) >> 6);
    if (wid >= nnz) return;
    int lane = threadIdx.x & 63;
    int r = rows[wid];
    int c = cols[wid];
    float v = vals[wid];
    float* op = out + (size_t)r * D + lane * 8;
#pragma unroll
    for (int k = 0; k < 8; ++k) {
        float wv = w[(size_t)(lane * 8 + k) * D + c];
        atomicAdd(&op[k], v * wv);
    }
}

extern "C" void kernel_launch(void* const* d_in, const int* in_sizes, int n_in,
                              void* d_out, int out_size, void* d_ws, size_t ws_size,
                              hipStream_t stream) {
    const int*   rows   = (const int*)d_in[0];
    const int*   cols   = (const int*)d_in[1];
    const float* vals   = (const float*)d_in[2];
    const float* weight = (const float*)d_in[3];
    const float* bias   = (const float*)d_in[4];
    float*       out    = (float*)d_out;
    const int nnz = in_sizes[0];

    // workspace carve-out
    char* ws = (char*)d_ws;
    size_t off = 0;
    auto alloc = [&](size_t bytes) -> void* {
        off = (off + 255) & ~(size_t)255;
        void* p = ws + off;
        off += bytes;
        return p;
    };
    __hip_bfloat16* wT = (__hip_bfloat16*)alloc((size_t)D * D * sizeof(__hip_bfloat16)); // 512 KiB
    int*   counts  = (int*)  alloc((size_t)NROWS * sizeof(int));                // 256 KiB
    int*   ovf_cnt = (int*)  alloc(256);                                        // 1 int
    uint4* ovf     = (uint4*)alloc((size_t)OVFCAP * sizeof(uint4));             // 64 KiB
    uint2* bucket  = (uint2*)alloc((size_t)NROWS * CAP * sizeof(uint2));        // 16 MiB
    const size_t need_full = off;

    if (need_full <= ws_size) {
        // ---- bucket path: 3 dispatches, transpose fused under the scatter ----
        const int nnzBlocks = (nnz + 255) / 256;
        k_zero<<<NROWS / 1024, 256, 0, stream>>>(counts, ovf_cnt);
        k_bucket<<<256 + nnzBlocks, 256, 0, stream>>>(weight, wT, rows, cols, vals, nnz,
                                                      counts, bucket, ovf_cnt, ovf);
        k_spmm<<<NROWS / 4, 256, 0, stream>>>(counts, bucket, (const uint4*)wT,
                                              (const f32x4*)bias, (f32x4*)out, ovf_cnt, ovf);
    } else {
        // ---- atomic fallback, direct (strided) weight reads ----
        k_init_bias<<<(out_size + 255) / 256, 256, 0, stream>>>(bias, out, out_size);
        k_atomic_spmm<<<((size_t)nnz * 64 + 255) / 256, 256, 0, stream>>>(rows, cols, vals, nnz, weight, out);
    }
}